// Round 3
// baseline (819.188 us; speedup 1.0000x reference)
//
#include <hip/hip_runtime.h>

#define NN 100000
#define NE 3200000
#define DD 256
#define NCHUNK 98   // ceil(NN/1024)
#define NTILES 3125 // NN/32
#define GGRID 512   // gemm persistent blocks

// ---------- helpers ----------
static __device__ __forceinline__ unsigned short f2bf(float f) {
    unsigned u = __float_as_uint(f);
    return (unsigned short)((u + 0x7fffu + ((u >> 16) & 1u)) >> 16);
}
static __device__ __forceinline__ float bflo(unsigned v) { return __uint_as_float(v << 16); }
static __device__ __forceinline__ float bfhi(unsigned v) { return __uint_as_float(v & 0xffff0000u); }

// ---------- degree ----------
__global__ void k_init_deg(int* __restrict__ deg) {
    int i = blockIdx.x * 256 + threadIdx.x;
    if (i < NN) deg[i] = 1;  // unit self-loop
}

__global__ void k_count(const int* __restrict__ src, int* __restrict__ deg) {
    int e = blockIdx.x * 256 + threadIdx.x;  // grid covers NE exactly
    atomicAdd(&deg[src[e]], 1);
}

// ---------- two-level exclusive scan of cnt = deg-1 ----------
__global__ void k_chunksum(const int* __restrict__ deg, int* __restrict__ csum) {
    __shared__ int s[256];
    int b = blockIdx.x, t = threadIdx.x;
    int base = b * 1024 + t * 4;
    int sum = 0;
#pragma unroll
    for (int j = 0; j < 4; ++j) {
        int i = base + j;
        if (i < NN) sum += deg[i] - 1;
    }
    s[t] = sum;
    __syncthreads();
    for (int d = 128; d > 0; d >>= 1) {
        if (t < d) s[t] += s[t + d];
        __syncthreads();
    }
    if (t == 0) csum[b] = s[0];
}

__global__ void k_scanchunks(int* __restrict__ csum) {
    __shared__ int s[128];
    int t = threadIdx.x;
    int v = (t < NCHUNK) ? csum[t] : 0;
    s[t] = v;
    __syncthreads();
    for (int d = 1; d < 128; d <<= 1) {
        int u = (t >= d) ? s[t - d] : 0;
        __syncthreads();
        s[t] += u;
        __syncthreads();
    }
    if (t < NCHUNK) csum[t] = s[t] - v;  // exclusive
}

__global__ void k_scanwithin(const int* __restrict__ deg, const int* __restrict__ csum,
                             int* __restrict__ offs, int* __restrict__ woff,
                             float* __restrict__ dinv) {
    __shared__ int s[256];
    int b = blockIdx.x, t = threadIdx.x;
    int base = b * 1024 + t * 4;
    int c[4];
#pragma unroll
    for (int j = 0; j < 4; ++j) {
        int i = base + j;
        c[j] = (i < NN) ? deg[i] - 1 : 0;
    }
    int tsum = c[0] + c[1] + c[2] + c[3];
    s[t] = tsum;
    __syncthreads();
    for (int d = 1; d < 256; d <<= 1) {
        int v = (t >= d) ? s[t - d] : 0;
        __syncthreads();
        s[t] += v;
        __syncthreads();
    }
    int run = s[t] - tsum + csum[b];
#pragma unroll
    for (int j = 0; j < 4; ++j) {
        int i = base + j;
        if (i < NN) {
            offs[i] = run;
            woff[i] = run;
            dinv[i] = 1.0f / (float)deg[i];
            run += c[j];
        }
    }
}

// ---------- CSR scatter (weightless: adj holds dst only) ----------
__global__ void k_scatter(const int* __restrict__ src, const int* __restrict__ dst,
                          int* __restrict__ woff, int* __restrict__ adj) {
    int e = blockIdx.x * 256 + threadIdx.x;  // grid covers NE exactly
    int s = src[e];
    int pos = atomicAdd(&woff[s], 1);
    adj[pos] = dst[e];
}

// ---------- Wt = bf16(W^T)  (256x256) ----------
__global__ void k_wt(const float* __restrict__ W, unsigned short* __restrict__ Wt) {
    int idx = blockIdx.x * 256 + threadIdx.x;
    int n = idx >> 8, k = idx & 255;
    Wt[n * 256 + k] = f2bf(W[k * 256 + n]);
}

// ---------- Z = bf16((X @ W) * dinv[row])  — persistent-B MFMA GEMM ----------
// Grid GGRID blocks x 256 thr (4 waves). Wave w owns output cols [64w, 64w+64):
// its B frags (Wt) live in registers for the whole kernel (32 x bf16x8 = 128 VGPR).
// Only the 32x256 A tile goes through LDS, double-buffered, 1 barrier/tile.
__global__ __launch_bounds__(256, 2) void k_gemm(const float* __restrict__ X,
                                                 const unsigned short* __restrict__ Wt,
                                                 const float* __restrict__ dinv,
                                                 unsigned short* __restrict__ Z) {
    using bf16x8 = __attribute__((ext_vector_type(8))) short;
    using f32x4 = __attribute__((ext_vector_type(4))) float;
    __shared__ unsigned short As[2][32 * 264];  // stride 264 shorts: conflict-spread

    int tid = threadIdx.x;
    int lane = tid & 63, w = tid >> 6;
    int mrow = lane & 15, quad = lane >> 4;

    // persistent B fragments: Bf[nt][k0]
    bf16x8 Bf[4][8];
#pragma unroll
    for (int nt = 0; nt < 4; ++nt)
#pragma unroll
        for (int k0 = 0; k0 < 8; ++k0)
            Bf[nt][k0] = *(const bf16x8*)(Wt + (size_t)(w * 64 + nt * 16 + mrow) * 256 + k0 * 32 + quad * 8);

    const float4* X4 = (const float4*)X;
    float4 sreg[8];

    auto load_tile = [&](int t) {
        int row0 = t * 32;
#pragma unroll
        for (int jj = 0; jj < 8; ++jj) {
            int g = jj * 256 + tid;
            int r = g >> 6, k4 = g & 63;
            sreg[jj] = X4[(size_t)(row0 + r) * 64 + k4];
        }
    };
    auto store_tile = [&](int buf) {
#pragma unroll
        for (int jj = 0; jj < 8; ++jj) {
            int g = jj * 256 + tid;
            int r = g >> 6, k4 = g & 63;
            ushort4 h;
            h.x = f2bf(sreg[jj].x);
            h.y = f2bf(sreg[jj].y);
            h.z = f2bf(sreg[jj].z);
            h.w = f2bf(sreg[jj].w);
            *(ushort4*)&As[buf][r * 264 + k4 * 4] = h;
        }
    };

    int t = blockIdx.x;
    load_tile(t);
    store_tile(0);
    __syncthreads();
    int buf = 0;

    for (;;) {
        int tn = t + GGRID;
        bool hn = tn < NTILES;
        if (hn) load_tile(tn);  // global loads in flight during compute

        f32x4 acc[2][4];
#pragma unroll
        for (int m = 0; m < 2; ++m)
#pragma unroll
            for (int nt = 0; nt < 4; ++nt) acc[m][nt] = (f32x4){0.f, 0.f, 0.f, 0.f};

#pragma unroll
        for (int k0 = 0; k0 < 8; ++k0) {
            bf16x8 af0 = *(const bf16x8*)&As[buf][(mrow) * 264 + k0 * 32 + quad * 8];
            bf16x8 af1 = *(const bf16x8*)&As[buf][(16 + mrow) * 264 + k0 * 32 + quad * 8];
#pragma unroll
            for (int nt = 0; nt < 4; ++nt) {
                acc[0][nt] = __builtin_amdgcn_mfma_f32_16x16x32_bf16(af0, Bf[nt][k0], acc[0][nt], 0, 0, 0);
                acc[1][nt] = __builtin_amdgcn_mfma_f32_16x16x32_bf16(af1, Bf[nt][k0], acc[1][nt], 0, 0, 0);
            }
        }

        // epilogue: Z[row] = bf16(acc * dinv[row]); C/D: col=mrow, row=quad*4+r
        int row0 = t * 32;
#pragma unroll
        for (int m = 0; m < 2; ++m) {
            int rbase = row0 + m * 16 + quad * 4;
            float4 dv = *(const float4*)&dinv[rbase];
            float dva[4] = {dv.x, dv.y, dv.z, dv.w};
#pragma unroll
            for (int nt = 0; nt < 4; ++nt) {
                int col = w * 64 + nt * 16 + mrow;
#pragma unroll
                for (int r = 0; r < 4; ++r)
                    Z[(size_t)(rbase + r) * 256 + col] = f2bf(acc[m][nt][r] * dva[r]);
            }
        }

        if (!hn) break;
        store_tile(buf ^ 1);
        __syncthreads();
        buf ^= 1;
        t = tn;
    }
}

// ---------- out = Z[i] + sum Z[adj] : one wave/node, unroll-8 row gathers ----------
__global__ __launch_bounds__(256) void k_spmm(const uint2* __restrict__ Zp,
                                              const int* __restrict__ adj,
                                              const int* __restrict__ offs,
                                              const int* __restrict__ deg,
                                              float* __restrict__ out) {
    int w = threadIdx.x >> 6;
    int lane = threadIdx.x & 63;
    int i = blockIdx.x * 4 + w;  // grid 25000 exact

    uint2 v = Zp[(size_t)i * 64 + lane];
    float a0 = bflo(v.x), a1 = bfhi(v.x);
    float a2 = bflo(v.y), a3 = bfhi(v.y);

    int off = offs[i];
    int cnt = deg[i] - 1;
    const int* e = adj + off;
    int kmain = cnt & ~7;

    for (int k = 0; k < kmain; k += 8) {
        int j[8];
#pragma unroll
        for (int u = 0; u < 8; ++u) j[u] = e[k + u];
        uint2 r[8];
#pragma unroll
        for (int u = 0; u < 8; ++u) r[u] = Zp[(size_t)j[u] * 64 + lane];
#pragma unroll
        for (int u = 0; u < 8; ++u) {
            a0 += bflo(r[u].x);
            a1 += bfhi(r[u].x);
            a2 += bflo(r[u].y);
            a3 += bfhi(r[u].y);
        }
    }
    if (kmain < cnt) {
#pragma unroll
        for (int u = 0; u < 8; ++u) {
            int idx = kmain + u;
            int cl = idx < cnt ? idx : cnt - 1;
            int j = e[cl];
            uint2 r = Zp[(size_t)j * 64 + lane];
            if (idx < cnt) {
                a0 += bflo(r.x);
                a1 += bfhi(r.x);
                a2 += bflo(r.y);
                a3 += bfhi(r.y);
            }
        }
    }

    *(float4*)(out + (size_t)i * 256 + lane * 4) = make_float4(a0, a1, a2, a3);
}

extern "C" void kernel_launch(void* const* d_in, const int* in_sizes, int n_in,
                              void* d_out, int out_size, void* d_ws, size_t ws_size,
                              hipStream_t stream) {
    const float* X = (const float*)d_in[0];
    const int* ei = (const int*)d_in[1];
    const float* W = (const float*)d_in[2];
    const int* src = ei;       // edge_index[0]
    const int* dst = ei + NE;  // edge_index[1]
    float* out = (float*)d_out;

    char* p = (char*)d_ws;
    auto alloc = [&](size_t bytes) {
        void* r = (void*)p;
        p += (bytes + 511) & ~(size_t)511;
        return r;
    };
    int* deg = (int*)alloc((size_t)NN * 4);
    int* offs = (int*)alloc((size_t)NN * 4);
    int* woff = (int*)alloc((size_t)NN * 4);
    int* csum = (int*)alloc((size_t)NCHUNK * 4);
    float* dinv = (float*)alloc((size_t)NN * 4);
    int* adj = (int*)alloc(((size_t)NE + 16) * 4);
    unsigned short* Wt = (unsigned short*)alloc((size_t)DD * DD * 2);
    unsigned short* Z = (unsigned short*)alloc((size_t)NN * DD * 2);

    k_init_deg<<<(NN + 255) / 256, 256, 0, stream>>>(deg);
    k_count<<<NE / 256, 256, 0, stream>>>(src, deg);
    k_chunksum<<<NCHUNK, 256, 0, stream>>>(deg, csum);
    k_scanchunks<<<1, 128, 0, stream>>>(csum);
    k_scanwithin<<<NCHUNK, 256, 0, stream>>>(deg, csum, offs, woff, dinv);
    k_wt<<<DD * DD / 256, 256, 0, stream>>>(W, Wt);
    k_gemm<<<GGRID, 256, 0, stream>>>(X, Wt, dinv, Z);
    k_scatter<<<NE / 256, 256, 0, stream>>>(src, dst, woff, adj);
    k_spmm<<<NN / 4, 256, 0, stream>>>((const uint2*)Z, adj, offs, deg, out);
}